// Round 4
// baseline (470.306 us; speedup 1.0000x reference)
//
#include <hip/hip_runtime.h>
#include <stdint.h>

#define M_NODES 100000
#define M_PAD   100096               // divisible by 128 (782 tiles of 128 rows)
#define NE      600000
#define DIM     128
#define NGRAPH  64
#define SCAN_B  512
#define SCAN_NB ((M_NODES + SCAN_B - 1) / SCAN_B)   // 196
#define WP      136   // sZ pitch in halves (row stride 272 B, 16B-aligned chunks)

typedef __attribute__((ext_vector_type(8))) short short8;
typedef __attribute__((ext_vector_type(4))) float f32x4;

// ---- bf16 helpers (manual, RNE) ----
__device__ inline float bf2lo(uint32_t u) { return __uint_as_float(u << 16); }
__device__ inline float bf2hi(uint32_t u) { return __uint_as_float(u & 0xffff0000u); }
__device__ inline uint32_t packbf2(float a, float b) {
    uint32_t ua = __float_as_uint(a), ub = __float_as_uint(b);
    ua += 0x7fffu + ((ua >> 16) & 1u);
    ub += 0x7fffu + ((ub >> 16) & 1u);
    return (ua >> 16) | (ub & 0xffff0000u);
}
__device__ inline uint16_t ftobf16(float f) {
    uint32_t u = __float_as_uint(f);
    u += 0x7fffu + ((u >> 16) & 1u);
    return (uint16_t)(u >> 16);
}

// async 16B global->LDS copy (direct DMA, no VGPR round-trip); vmcnt-tracked,
// drained by the s_waitcnt before s_barrier. LDS dest = wave-uniform base +
// lane*16 (HW rule) -- caller must pass a lane-invariant lds pointer.
__device__ inline void async_copy16(const uint16_t* g, uint16_t* l) {
    __builtin_amdgcn_global_load_lds(
        (const __attribute__((address_space(1))) uint32_t*)g,
        (__attribute__((address_space(3))) uint32_t*)l, 16, 0, 0);
}

// ---- merged setup: embed + weight frag-order cvt + zero counters + graph bounds ----
// wfrag layout per layer L: [W1p, W1i, W2p, W2i], each 16384 halves in MFMA-fragment
// order: frag[((t*4+s)*64 + lane)*8 + j] = W[s*32+q*8+j][t*16+l16]  (lane = q*16+l16)
#define GB_EMBED 25000                 // M_NODES*64/256
#define GB_TRANS (GB_EMBED + 12)
#define GB_ZERO  (GB_TRANS + 391)
#define GB_BOUND (GB_ZERO + 391)
__global__ void k_setup(const int* __restrict__ x, const float2* __restrict__ te2,
                        const float2* __restrict__ oe2, uint32_t* __restrict__ h2,
                        const float* __restrict__ w1, const float* __restrict__ w2,
                        uint16_t* __restrict__ wfrag,
                        const int* __restrict__ batch, int* __restrict__ starts,
                        int* __restrict__ degp, int* __restrict__ degi) {
    int b = blockIdx.x, t = threadIdx.x;
    if (b < GB_EMBED) {                       // node input embedding
        int id = b * 256 + t;
        int node = id >> 6, p = id & 63;
        int x0 = x[node * 2], x1 = x[node * 2 + 1];
        float2 a = te2[x0 * 64 + p], bb = oe2[x1 * 64 + p];
        h2[node * 64 + p] = packbf2(a.x + bb.x, a.y + bb.y);
    } else if (b < GB_TRANS) {                // frag-order cvt of 12 weight matrices
        int m = b - GB_EMBED;
        const float* src;
        uint16_t* dst;
        if (m < 6) {
            int L = m >> 1, rel = m & 1;
            src = w1 + m * 16384;
            dst = wfrag + (size_t)(L * 4 + rel) * 16384;
        } else {
            int mm = m - 6, L = mm >> 1, rel = mm & 1;
            src = w2 + mm * 16384;
            dst = wfrag + (size_t)(L * 4 + 2 + rel) * 16384;
        }
        for (int o = t; o < 16384; o += 256) {
            int f = o >> 3, j = o & 7;
            int fb = f >> 6, ln = f & 63;
            int t_ = fb >> 2, s_ = fb & 3, qq = ln >> 4, ll = ln & 15;
            dst[o] = ftobf16(src[(s_ * 32 + qq * 8 + j) * 128 + t_ * 16 + ll]);
        }
    } else if (b < GB_ZERO) {                 // zero degree counters
        int i = (b - GB_TRANS) * 256 + t;
        if (i < M_NODES) { degp[i] = 0; degi[i] = 0; }
    } else {                                  // graph boundaries from sorted batch
        int i = (b - GB_ZERO) * 256 + t;
        if (i >= M_NODES) return;
        int bb = batch[i];
        int pb = (i == 0) ? -1 : batch[i - 1];
        for (int g = pb + 1; g <= bb; ++g) starts[g] = i;
        if (i == M_NODES - 1)
            for (int g = bb + 1; g <= NGRAPH; ++g) starts[g] = M_NODES;
    }
}

// ---- CSR build: histogram WITH slot capture, 3-kernel scan, atomic-free fill ----
// The returning atomicAdd hands every edge a stable slot within its destination's
// adjacency list; k_fill then needs no atomics, no windows, and one pass.
__global__ void k_hist(const int* __restrict__ ep, const int* __restrict__ ei,
                       int* __restrict__ degp, int* __restrict__ degi,
                       int* __restrict__ slotp, int* __restrict__ sloti) {
    int e = blockIdx.x * blockDim.x + threadIdx.x;
    if (e >= NE) return;
    slotp[e] = atomicAdd(&degp[ep[NE + e]], 1);
    sloti[e] = atomicAdd(&degi[ei[NE + e]], 1);
}

__global__ void k_scan1(const int* __restrict__ degp, const int* __restrict__ degi,
                        int* __restrict__ rsp, int* __restrict__ rsi, int* __restrict__ bsum) {
    __shared__ int s[SCAN_B];
    int list = blockIdx.y;
    const int* deg = list ? degi : degp;
    int* rs = list ? rsi : rsp;
    int i = blockIdx.x * SCAN_B + threadIdx.x;
    int v = (i < M_NODES) ? deg[i] : 0;
    s[threadIdx.x] = v;
    __syncthreads();
    for (int off = 1; off < SCAN_B; off <<= 1) {
        int xv = (threadIdx.x >= off) ? s[threadIdx.x - off] : 0;
        __syncthreads();
        s[threadIdx.x] += xv;
        __syncthreads();
    }
    if (i < M_NODES) rs[i + 1] = s[threadIdx.x];
    if (threadIdx.x == SCAN_B - 1) bsum[list * SCAN_NB + blockIdx.x] = s[threadIdx.x];
}

__global__ void k_scan2(const int* __restrict__ bsum, int* __restrict__ boff) {
    __shared__ int s[256];
    int list = blockIdx.x, t = threadIdx.x;
    int v = (t < SCAN_NB) ? bsum[list * SCAN_NB + t] : 0;
    s[t] = v;
    __syncthreads();
    for (int off = 1; off < 256; off <<= 1) {
        int xv = (t >= off) ? s[t - off] : 0;
        __syncthreads();
        s[t] += xv;
        __syncthreads();
    }
    if (t < SCAN_NB) boff[list * SCAN_NB + t] = s[t] - v;  // exclusive
}

__global__ void k_scan3(int* __restrict__ rsp, int* __restrict__ rsi, const int* __restrict__ boff) {
    int list = blockIdx.y;
    int* rs = list ? rsi : rsp;
    int i = blockIdx.x * SCAN_B + threadIdx.x;
    if (i < M_NODES) rs[i + 1] += boff[list * SCAN_NB + blockIdx.x];
    if (i == 0 && list == 0) { rsp[0] = 0; rsi[0] = 0; }
}

// Atomic-free scatter fill: one edge per thread, both relations.
__global__ void k_fill(const int* __restrict__ ep, const int* __restrict__ ei,
                       const int* __restrict__ rsp, const int* __restrict__ rsi,
                       const int* __restrict__ slotp, const int* __restrict__ sloti,
                       int* __restrict__ csrp, int* __restrict__ csri) {
    int e = blockIdx.x * blockDim.x + threadIdx.x;
    if (e >= NE) return;
    int dp = ep[NE + e], sp = ep[e], kp = slotp[e];
    int di = ei[NE + e], si = ei[e], ki = sloti[e];
    csrp[rsp[dp] + kp] = sp;
    csri[rsi[di] + ki] = si;
}

// ---- fused dual-list aggregate: u = bf16(h + sum h[src]); 16 lanes x 8 dims per node ----
__device__ inline void add8(float* a, uint4 v) {
    a[0] += bf2lo(v.x); a[1] += bf2hi(v.x);
    a[2] += bf2lo(v.y); a[3] += bf2hi(v.y);
    a[4] += bf2lo(v.z); a[5] += bf2hi(v.z);
    a[6] += bf2lo(v.w); a[7] += bf2hi(v.w);
}

// Latency-bound random gather. R2 lesson: loads must be UNCONDITIONAL or the
// compiler folds them against their adds (serial chain; VGPR=28 proved nothing
// stayed in flight). Here: clamped indices (OOB lanes re-read the list's last
// element -> same-address L1 hit, free), value predication via cndmask AFTER
// the loads. Both relations share each round (3+3 = 6 outstanding 16B gathers);
// round count = ceil(max(dp,di)/3), so both lists drain in the same latency
// rounds. No launch_bounds: R1's proven config; compiler batches freely.
#define AGG_W 3
__global__ void k_aggregate2(const uint4* __restrict__ h4,
                             const int* __restrict__ rsp, const int* __restrict__ csrp,
                             const int* __restrict__ rsi, const int* __restrict__ csri,
                             uint4* __restrict__ up, uint4* __restrict__ ui) {
    int id = blockIdx.x * blockDim.x + threadIdx.x;  // [0, M*16)
    int node = id >> 4, p = id & 15;
    if (node >= M_NODES) return;
    uint4 hv = h4[(size_t)node * 16 + p];
    float a[8] = {bf2lo(hv.x), bf2hi(hv.x), bf2lo(hv.y), bf2hi(hv.y),
                  bf2lo(hv.z), bf2hi(hv.z), bf2lo(hv.w), bf2hi(hv.w)};
    float b[8];
#pragma unroll
    for (int j = 0; j < 8; ++j) b[j] = a[j];
    int ea = rsp[node], e1a = rsp[node + 1];
    int eb = rsi[node], e1b = rsi[node + 1];
    int la = max(e1a - 1, 0);           // clamp target (valid even for empty list)
    int lb = max(e1b - 1, 0);
    int da = e1a - ea, db = e1b - eb;
    int work = max(da, db);
    for (int done = 0; done < work; done += AGG_W) {
        int ia[AGG_W], ib[AGG_W];
#pragma unroll
        for (int j = 0; j < AGG_W; ++j) {
            ia[j] = csrp[min(ea + done + j, la)];
            ib[j] = csri[min(eb + done + j, lb)];
        }
        uint4 va[AGG_W], vb[AGG_W];
#pragma unroll
        for (int j = 0; j < AGG_W; ++j) {
            va[j] = h4[(size_t)ia[j] * 16 + p];
            vb[j] = h4[(size_t)ib[j] * 16 + p];
        }
        const uint4 z4 = make_uint4(0u, 0u, 0u, 0u);
#pragma unroll
        for (int j = 0; j < AGG_W; ++j) {
            uint4 xa = (done + j < da) ? va[j] : z4;   // value-predication (cndmask)
            uint4 xb = (done + j < db) ? vb[j] : z4;
            add8(a, xa);
            add8(b, xb);
        }
    }
    up[(size_t)node * 16 + p] = make_uint4(packbf2(a[0], a[1]), packbf2(a[2], a[3]),
                                           packbf2(a[4], a[5]), packbf2(a[6], a[7]));
    ui[(size_t)node * 16 + p] = make_uint4(packbf2(b[0], b[1]), packbf2(b[2], b[3]),
                                           packbf2(b[4], b[5]), packbf2(b[6], b[7]));
}

// ---- fused dual-relation MLP, 2 row-tiles (128 rows) per block ----
// r16 structure; weight staging via async global_load_lds (16B DMA).
__launch_bounds__(256, 2)
__global__ void k_gemm2(const uint16_t* __restrict__ Up, const uint16_t* __restrict__ Ui,
                        const uint16_t* __restrict__ WF1p, const float* __restrict__ B1p,
                        const uint16_t* __restrict__ WF2p, const float* __restrict__ B2p,
                        const uint16_t* __restrict__ WF1i, const float* __restrict__ B1i,
                        const uint16_t* __restrict__ WF2i, const float* __restrict__ B2i,
                        float* __restrict__ HN, uint16_t* __restrict__ HOUT, int last) {
    __shared__ __align__(16) uint16_t wbuf[16384];        // 32768 B, fragment-order
    __shared__ __align__(16) uint16_t sZ[2][64 * WP];     // 2 x 17408 B, wave-private
    int tid = threadIdx.x;
    int wave = tid >> 6, lane = tid & 63;
    int q = lane >> 4, l16 = lane & 15;
    int rb0 = blockIdx.x * 128 + wave * 16;   // tile 0 rows (this wave's 16)
    int rb1 = rb0 + 64;                       // tile 1 rows

    auto loadA = [&](const uint16_t* U, int rowbase, short8* v) {
        const uint16_t* P = U + (size_t)(rowbase + l16) * DIM + q * 8;
#pragma unroll
        for (int s = 0; s < 4; ++s) v[s] = *(const short8*)(P + s * 32);
    };
    // async weight staging: 8 x 16B per thread, direct global->LDS DMA.
    auto loadw = [&](const uint16_t* WF) {
#pragma unroll
        for (int k = 0; k < 8; ++k)
            async_copy16(WF + (size_t)(tid + k * 256) * 8,
                         &wbuf[(size_t)wave * 512 + (size_t)k * 2048]);
    };
    auto stage1 = [&](const short8* af, const float* B1, int zslot) {
        f32x4 acc1[8];
#pragma unroll
        for (int t = 0; t < 8; ++t) acc1[t] = (f32x4){0.f, 0.f, 0.f, 0.f};
#pragma unroll
        for (int t = 0; t < 8; ++t)
#pragma unroll
            for (int s = 0; s < 4; ++s) {
                short8 bb = *(const short8*)&wbuf[((t * 4 + s) * 64 + lane) * 8];
                acc1[t] = __builtin_amdgcn_mfma_f32_16x16x32_bf16(af[s], bb, acc1[t], 0, 0, 0);
            }
#pragma unroll
        for (int t = 0; t < 8; ++t) {
            float b1v = B1[t * 16 + l16];
#pragma unroll
            for (int r = 0; r < 4; ++r)
                sZ[zslot][(wave * 16 + q * 4 + r) * WP + t * 16 + l16] =
                    ftobf16(fmaxf(acc1[t][r] + b1v, 0.f));
        }
    };
    auto stage2 = [&](int zslot, f32x4* acc2) {
        short8 zf[4];
#pragma unroll
        for (int s = 0; s < 4; ++s)
            zf[s] = *(const short8*)&sZ[zslot][(wave * 16 + l16) * WP + s * 32 + q * 8];
#pragma unroll
        for (int t = 0; t < 8; ++t)
#pragma unroll
            for (int s = 0; s < 4; ++s) {
                short8 bb = *(const short8*)&wbuf[((t * 4 + s) * 64 + lane) * 8];
                acc2[t] = __builtin_amdgcn_mfma_f32_16x16x32_bf16(zf[s], bb, acc2[t], 0, 0, 0);
            }
    };

    f32x4 acc2a[8], acc2b[8];
#pragma unroll
    for (int t = 0; t < 8; ++t) { acc2a[t] = (f32x4){0.f,0.f,0.f,0.f}; acc2b[t] = (f32x4){0.f,0.f,0.f,0.f}; }

    short8 af0[4], af1[4];
    loadw(WF1p);                                       // async, in flight
    loadA(Up, rb0, af0); loadA(Up, rb1, af1);          // relation-p A frags in flight
    __syncthreads();                                   // drains vmcnt: wbuf = W1p
    stage1(af0, B1p, 0); stage1(af1, B1p, 1);
    __syncthreads();                                   // W1p reads done
    loadw(WF2p); __syncthreads();                      // wbuf = W2p
    stage2(0, acc2a); stage2(1, acc2b);
    __syncthreads();                                   // W2p reads done
    loadw(WF1i);                                       // async
    loadA(Ui, rb0, af0); loadA(Ui, rb1, af1);          // relation-i A frags
    __syncthreads();                                   // wbuf = W1i
    stage1(af0, B1i, 0); stage1(af1, B1i, 1);
    __syncthreads();
    loadw(WF2i); __syncthreads();                      // wbuf = W2i
    stage2(0, acc2a); stage2(1, acc2b);

    // epilogue, both tiles
#pragma unroll
    for (int t = 0; t < 8; ++t) {
        int col = t * 16 + l16;
        float b2v = B2p[col] + B2i[col];
#pragma unroll
        for (int r = 0; r < 4; ++r) {
            int row0 = rb0 + q * 4 + r, row1 = rb1 + q * 4 + r;
            float y0 = acc2a[t][r] + b2v, y1 = acc2b[t][r] + b2v;
            if (last) {
                HN[(size_t)row0 * DIM + col] = y0;
                HN[(size_t)row1 * DIM + col] = y1;
            } else {
                HOUT[(size_t)row0 * DIM + col] = ftobf16(fmaxf(y0, 0.f));
                HOUT[(size_t)row1 * DIM + col] = ftobf16(fmaxf(y1, 0.f));
            }
        }
    }
}

// ---- pooling, two-stage, high-parallelism (1024 + 64 blocks) ----
__global__ void k_pool1(const float* __restrict__ HN, const int* __restrict__ starts,
                        float* __restrict__ psum, float* __restrict__ pmax, float* __restrict__ pmin) {
    int g = blockIdx.x, sp = blockIdx.y, t = threadIdx.x;  // 256 threads = 2 row-slots x 128 dims
    int d = t & 127, rh = t >> 7;
    int slot = sp * 2 + rh;                                 // 0..31
    int s0 = starts[g], s1 = starts[g + 1];
    float s = 0.f, mx = -INFINITY, mn = INFINITY;
    for (int i = s0 + slot; i < s1; i += 32) {
        float v = HN[(size_t)i * DIM + d];
        s += v; mx = fmaxf(mx, v); mn = fminf(mn, v);
    }
    int o = (g * 32 + slot) * DIM + d;
    psum[o] = s; pmax[o] = mx; pmin[o] = mn;
}

__global__ void k_pool2(const float* __restrict__ psum, const float* __restrict__ pmax,
                        const float* __restrict__ pmin, const int* __restrict__ starts,
                        float* __restrict__ out) {
    __shared__ float S[4][128];
    int g = blockIdx.x, t = threadIdx.x;  // 128 threads
    float s = 0.f, mx = -INFINITY, mn = INFINITY;
    for (int p = 0; p < 32; ++p) {
        int o = (g * 32 + p) * DIM + t;
        s += psum[o]; mx = fmaxf(mx, pmax[o]); mn = fminf(mn, pmin[o]);
    }
    float cnt = (float)(starts[g + 1] - starts[g]);
    float mean = s / fmaxf(cnt, 1.f);
    S[0][t] = s; S[1][t] = mean; S[2][t] = mx; S[3][t] = mn;
    __syncthreads();
    // out[g,k,d] = concat[g, 4d+k]; concat = [sum|mean|max|min]
#pragma unroll
    for (int k = 0; k < 4; ++k) {
        int j = 4 * t + k;
        out[g * 512 + k * 128 + t] = S[j >> 7][j & 127];
    }
    if (t < 4) out[NGRAPH * 512 + g * 4 + t] = 1.0f;  // batch_mask = True -> 1.0f
}

extern "C" void kernel_launch(void* const* d_in, const int* in_sizes, int n_in,
                              void* d_out, int out_size, void* d_ws, size_t ws_size,
                              hipStream_t stream) {
    const int* x     = (const int*)d_in[0];
    const int* ep    = (const int*)d_in[1];
    const int* ei    = (const int*)d_in[2];
    const int* batch = (const int*)d_in[3];
    const float* te  = (const float*)d_in[4];
    const float* oe  = (const float*)d_in[5];
    const float* w1  = (const float*)d_in[6];
    const float* b1  = (const float*)d_in[7];
    const float* w2  = (const float*)d_in[8];
    const float* b2  = (const float*)d_in[9];
    float* out = (float*)d_out;

    char* w = (char*)d_ws;
    auto alloc = [&](size_t n) { char* p = w; w += (n + 255) & ~(size_t)255; return p; };
    uint16_t* h_bf  = (uint16_t*)alloc((size_t)M_PAD * DIM * 2);
    uint16_t* u_pos = (uint16_t*)alloc((size_t)M_PAD * DIM * 2);
    uint16_t* u_inv = (uint16_t*)alloc((size_t)M_PAD * DIM * 2);
    float*    hn    = (float*)alloc((size_t)M_PAD * DIM * 4);
    uint16_t* wfrag = (uint16_t*)alloc((size_t)12 * 16384 * 2);
    int* rsp  = (int*)alloc((M_NODES + 2) * 4);
    int* rsi  = (int*)alloc((M_NODES + 2) * 4);
    int* degp = (int*)alloc(M_NODES * 4);
    int* degi = (int*)alloc(M_NODES * 4);
    int* csrp = (int*)alloc((size_t)NE * 4);
    int* csri = (int*)alloc((size_t)NE * 4);
    int* bsum = (int*)alloc(2 * SCAN_NB * 4);
    int* boff = (int*)alloc(2 * SCAN_NB * 4);
    int* starts = (int*)alloc((NGRAPH + 1) * 4);
    float* psum = (float*)alloc(NGRAPH * 32 * DIM * 4);
    float* pmax = (float*)alloc(NGRAPH * 32 * DIM * 4);
    float* pmin = (float*)alloc(NGRAPH * 32 * DIM * 4);
    if ((size_t)(w - (char*)d_ws) > ws_size) return;  // fail loudly rather than corrupt

    // Per-edge slot arrays alias u_pos/u_inv (25.6 MB each, dead until
    // k_aggregate2 rewrites them AFTER k_fill is done) -> zero extra workspace.
    int* slotp = (int*)u_pos;
    int* sloti = (int*)u_inv;

    k_setup<<<GB_BOUND, 256, 0, stream>>>(x, (const float2*)te, (const float2*)oe,
                                          (uint32_t*)h_bf, w1, w2, wfrag,
                                          batch, starts, degp, degi);
    k_hist<<<(NE + 255) / 256, 256, 0, stream>>>(ep, ei, degp, degi, slotp, sloti);
    dim3 gs(SCAN_NB, 2);
    k_scan1<<<gs, SCAN_B, 0, stream>>>(degp, degi, rsp, rsi, bsum);
    k_scan2<<<2, 256, 0, stream>>>(bsum, boff);
    k_scan3<<<gs, SCAN_B, 0, stream>>>(rsp, rsi, boff);
    k_fill<<<(NE + 255) / 256, 256, 0, stream>>>(ep, ei, rsp, rsi, slotp, sloti, csrp, csri);

    for (int l = 0; l < 3; ++l) {
        k_aggregate2<<<(M_NODES * 16 + 255) / 256, 256, 0, stream>>>(
            (const uint4*)h_bf, rsp, csrp, rsi, csri, (uint4*)u_pos, (uint4*)u_inv);
        const uint16_t* wfL = wfrag + (size_t)l * 4 * 16384;
        // wfrag per layer: [W1p, W1i, W2p, W2i]
        k_gemm2<<<M_PAD / 128, 256, 0, stream>>>(
            u_pos, u_inv,
            wfL,              b1 + (2 * l) * 128,
            wfL + 2 * 16384,  b2 + (2 * l) * 128,
            wfL + 16384,      b1 + (2 * l + 1) * 128,
            wfL + 3 * 16384,  b2 + (2 * l + 1) * 128,
            hn, h_bf, (l == 2) ? 1 : 0);
    }
    dim3 gp(NGRAPH, 16);
    k_pool1<<<gp, 256, 0, stream>>>(hn, starts, psum, pmax, pmin);
    k_pool2<<<NGRAPH, 128, 0, stream>>>(psum, pmax, pmin, starts, out);
}

// Round 5
// 455.882 us; speedup vs baseline: 1.0316x; 1.0316x over previous
//
#include <hip/hip_runtime.h>
#include <stdint.h>

#define M_NODES 100000
#define M_PAD   100096               // divisible by 128 (782 tiles of 128 rows)
#define NE      600000
#define DIM     128
#define NGRAPH  64
#define SCAN_B  512
#define SCAN_NB ((M_NODES + SCAN_B - 1) / SCAN_B)   // 196
#define WP      136   // sZ pitch in halves (row stride 272 B, 16B-aligned chunks)

typedef __attribute__((ext_vector_type(8))) short short8;
typedef __attribute__((ext_vector_type(4))) float f32x4;
typedef __attribute__((ext_vector_type(4))) unsigned int u32x4;

// ---- bf16 helpers (manual, RNE) ----
__device__ inline float bf2lo(uint32_t u) { return __uint_as_float(u << 16); }
__device__ inline float bf2hi(uint32_t u) { return __uint_as_float(u & 0xffff0000u); }
__device__ inline uint32_t packbf2(float a, float b) {
    uint32_t ua = __float_as_uint(a), ub = __float_as_uint(b);
    ua += 0x7fffu + ((ua >> 16) & 1u);
    ub += 0x7fffu + ((ub >> 16) & 1u);
    return (ua >> 16) | (ub & 0xffff0000u);
}
__device__ inline uint16_t ftobf16(float f) {
    uint32_t u = __float_as_uint(f);
    u += 0x7fffu + ((u >> 16) & 1u);
    return (uint16_t)(u >> 16);
}

// async 16B global->LDS copy (direct DMA, no VGPR round-trip); vmcnt-tracked,
// drained by the s_waitcnt before s_barrier. LDS dest = wave-uniform base +
// lane*16 (HW rule) -- caller must pass a lane-invariant lds pointer.
__device__ inline void async_copy16(const uint16_t* g, uint16_t* l) {
    __builtin_amdgcn_global_load_lds(
        (const __attribute__((address_space(1))) uint32_t*)g,
        (__attribute__((address_space(3))) uint32_t*)l, 16, 0, 0);
}

// Opaque 16B global load: the compiler CANNOT sink/fold this against its
// consumer (R2/R4 failure mode: hipcc serialized every C-level gather,
// VGPR=28/32 proved nothing stayed in flight). Early-clobber dst.
__device__ inline u32x4 gload16(const u32x4* p) {
    u32x4 r;
    asm volatile("global_load_dwordx4 %0, %1, off" : "=&v"(r) : "v"(p));
    return r;
}

// ---- merged setup: embed + weight frag-order cvt + zero counters + graph bounds ----
// wfrag layout per layer L: [W1p, W1i, W2p, W2i], each 16384 halves in MFMA-fragment
// order: frag[((t*4+s)*64 + lane)*8 + j] = W[s*32+q*8+j][t*16+l16]  (lane = q*16+l16)
#define GB_EMBED 25000                 // M_NODES*64/256
#define GB_TRANS (GB_EMBED + 12)
#define GB_ZERO  (GB_TRANS + 391)
#define GB_BOUND (GB_ZERO + 391)
__global__ void k_setup(const int* __restrict__ x, const float2* __restrict__ te2,
                        const float2* __restrict__ oe2, uint32_t* __restrict__ h2,
                        const float* __restrict__ w1, const float* __restrict__ w2,
                        uint16_t* __restrict__ wfrag,
                        const int* __restrict__ batch, int* __restrict__ starts,
                        int* __restrict__ degp, int* __restrict__ degi) {
    int b = blockIdx.x, t = threadIdx.x;
    if (b < GB_EMBED) {                       // node input embedding
        int id = b * 256 + t;
        int node = id >> 6, p = id & 63;
        int x0 = x[node * 2], x1 = x[node * 2 + 1];
        float2 a = te2[x0 * 64 + p], bb = oe2[x1 * 64 + p];
        h2[node * 64 + p] = packbf2(a.x + bb.x, a.y + bb.y);
    } else if (b < GB_TRANS) {                // frag-order cvt of 12 weight matrices
        int m = b - GB_EMBED;
        const float* src;
        uint16_t* dst;
        if (m < 6) {
            int L = m >> 1, rel = m & 1;
            src = w1 + m * 16384;
            dst = wfrag + (size_t)(L * 4 + rel) * 16384;
        } else {
            int mm = m - 6, L = mm >> 1, rel = mm & 1;
            src = w2 + mm * 16384;
            dst = wfrag + (size_t)(L * 4 + 2 + rel) * 16384;
        }
        for (int o = t; o < 16384; o += 256) {
            int f = o >> 3, j = o & 7;
            int fb = f >> 6, ln = f & 63;
            int t_ = fb >> 2, s_ = fb & 3, qq = ln >> 4, ll = ln & 15;
            dst[o] = ftobf16(src[(s_ * 32 + qq * 8 + j) * 128 + t_ * 16 + ll]);
        }
    } else if (b < GB_ZERO) {                 // zero degree counters
        int i = (b - GB_TRANS) * 256 + t;
        if (i < M_NODES) { degp[i] = 0; degi[i] = 0; }
    } else {                                  // graph boundaries from sorted batch
        int i = (b - GB_ZERO) * 256 + t;
        if (i >= M_NODES) return;
        int bb = batch[i];
        int pb = (i == 0) ? -1 : batch[i - 1];
        for (int g = pb + 1; g <= bb; ++g) starts[g] = i;
        if (i == M_NODES - 1)
            for (int g = bb + 1; g <= NGRAPH; ++g) starts[g] = M_NODES;
    }
}

// ---- CSR build: histogram WITH slot capture, 3-kernel scan, atomic-free fill ----
// The returning atomicAdd hands every edge a stable slot within its destination's
// adjacency list; k_fill then needs no atomics, no windows, and one pass.
__global__ void k_hist(const int* __restrict__ ep, const int* __restrict__ ei,
                       int* __restrict__ degp, int* __restrict__ degi,
                       int* __restrict__ slotp, int* __restrict__ sloti) {
    int e = blockIdx.x * blockDim.x + threadIdx.x;
    if (e >= NE) return;
    slotp[e] = atomicAdd(&degp[ep[NE + e]], 1);
    sloti[e] = atomicAdd(&degi[ei[NE + e]], 1);
}

__global__ void k_scan1(const int* __restrict__ degp, const int* __restrict__ degi,
                        int* __restrict__ rsp, int* __restrict__ rsi, int* __restrict__ bsum) {
    __shared__ int s[SCAN_B];
    int list = blockIdx.y;
    const int* deg = list ? degi : degp;
    int* rs = list ? rsi : rsp;
    int i = blockIdx.x * SCAN_B + threadIdx.x;
    int v = (i < M_NODES) ? deg[i] : 0;
    s[threadIdx.x] = v;
    __syncthreads();
    for (int off = 1; off < SCAN_B; off <<= 1) {
        int xv = (threadIdx.x >= off) ? s[threadIdx.x - off] : 0;
        __syncthreads();
        s[threadIdx.x] += xv;
        __syncthreads();
    }
    if (i < M_NODES) rs[i + 1] = s[threadIdx.x];
    if (threadIdx.x == SCAN_B - 1) bsum[list * SCAN_NB + blockIdx.x] = s[threadIdx.x];
}

__global__ void k_scan2(const int* __restrict__ bsum, int* __restrict__ boff) {
    __shared__ int s[256];
    int list = blockIdx.x, t = threadIdx.x;
    int v = (t < SCAN_NB) ? bsum[list * SCAN_NB + t] : 0;
    s[t] = v;
    __syncthreads();
    for (int off = 1; off < 256; off <<= 1) {
        int xv = (t >= off) ? s[t - off] : 0;
        __syncthreads();
        s[t] += xv;
        __syncthreads();
    }
    if (t < SCAN_NB) boff[list * SCAN_NB + t] = s[t] - v;  // exclusive
}

__global__ void k_scan3(int* __restrict__ rsp, int* __restrict__ rsi, const int* __restrict__ boff) {
    int list = blockIdx.y;
    int* rs = list ? rsi : rsp;
    int i = blockIdx.x * SCAN_B + threadIdx.x;
    if (i < M_NODES) rs[i + 1] += boff[list * SCAN_NB + blockIdx.x];
    if (i == 0 && list == 0) { rsp[0] = 0; rsi[0] = 0; }
}

// Atomic-free scatter fill: one edge per thread, both relations.
__global__ void k_fill(const int* __restrict__ ep, const int* __restrict__ ei,
                       const int* __restrict__ rsp, const int* __restrict__ rsi,
                       const int* __restrict__ slotp, const int* __restrict__ sloti,
                       int* __restrict__ csrp, int* __restrict__ csri) {
    int e = blockIdx.x * blockDim.x + threadIdx.x;
    if (e >= NE) return;
    int dp = ep[NE + e], sp = ep[e], kp = slotp[e];
    int di = ei[NE + e], si = ei[e], ki = sloti[e];
    csrp[rsp[dp] + kp] = sp;
    csri[rsi[di] + ki] = si;
}

// ---- fused dual-list aggregate: u = bf16(h + sum h[src]); 16 lanes x 8 dims per node ----
__device__ inline void add8v(float* a, u32x4 v) {
    a[0] += bf2lo(v[0]); a[1] += bf2hi(v[0]);
    a[2] += bf2lo(v[1]); a[3] += bf2hi(v[1]);
    a[4] += bf2lo(v[2]); a[5] += bf2hi(v[2]);
    a[6] += bf2lo(v[3]); a[7] += bf2hi(v[3]);
}

// Latency-bound random gather; the lever is memory-level parallelism. hipcc
// serialized every C-level batching attempt (R2/R4: VGPR=28/32). Fix: issue
// the 6 row gathers per round as OPAQUE inline-asm loads, then one
// s_waitcnt vmcnt(0) whose "+v" ties on all 6 results create true SSA deps
// (adds consume the waitcnt outputs -> no reordering hazard). Extra untracked
// loads only strengthen compiler-emitted vmcnt waits (in-order retirement),
// never weaken them. Indices are clamped (OOB lanes re-read the list's last
// element, L1-hit); value-predication via cndmask AFTER the waitcnt.
#define AGG_W 3
__global__ void k_aggregate2(const u32x4* __restrict__ h4,
                             const int* __restrict__ rsp, const int* __restrict__ csrp,
                             const int* __restrict__ rsi, const int* __restrict__ csri,
                             u32x4* __restrict__ up, u32x4* __restrict__ ui) {
    int id = blockIdx.x * blockDim.x + threadIdx.x;  // [0, M*16)
    int node = id >> 4, p = id & 15;
    if (node >= M_NODES) return;
    u32x4 hv = h4[(size_t)node * 16 + p];
    float a[8] = {bf2lo(hv[0]), bf2hi(hv[0]), bf2lo(hv[1]), bf2hi(hv[1]),
                  bf2lo(hv[2]), bf2hi(hv[2]), bf2lo(hv[3]), bf2hi(hv[3])};
    float b[8];
#pragma unroll
    for (int j = 0; j < 8; ++j) b[j] = a[j];
    int ea = rsp[node], e1a = rsp[node + 1];
    int eb = rsi[node], e1b = rsi[node + 1];
    int la = max(e1a - 1, 0);           // clamp target (valid even for empty list)
    int lb = max(e1b - 1, 0);
    int da = e1a - ea, db = e1b - eb;
    int work = max(da, db);
    for (int done = 0; done < work; done += AGG_W) {
        int i0 = csrp[min(ea + done + 0, la)];
        int i1 = csrp[min(ea + done + 1, la)];
        int i2 = csrp[min(ea + done + 2, la)];
        int j0 = csri[min(eb + done + 0, lb)];
        int j1 = csri[min(eb + done + 1, lb)];
        int j2 = csri[min(eb + done + 2, lb)];
        u32x4 va0 = gload16(h4 + ((size_t)i0 * 16 + p));
        u32x4 va1 = gload16(h4 + ((size_t)i1 * 16 + p));
        u32x4 va2 = gload16(h4 + ((size_t)i2 * 16 + p));
        u32x4 vb0 = gload16(h4 + ((size_t)j0 * 16 + p));
        u32x4 vb1 = gload16(h4 + ((size_t)j1 * 16 + p));
        u32x4 vb2 = gload16(h4 + ((size_t)j2 * 16 + p));
        asm volatile("s_waitcnt vmcnt(0)"
                     : "+v"(va0), "+v"(va1), "+v"(va2),
                       "+v"(vb0), "+v"(vb1), "+v"(vb2));
        const u32x4 z4 = {0u, 0u, 0u, 0u};
        add8v(a, (done + 0 < da) ? va0 : z4);   // value-predication (cndmask)
        add8v(a, (done + 1 < da) ? va1 : z4);
        add8v(a, (done + 2 < da) ? va2 : z4);
        add8v(b, (done + 0 < db) ? vb0 : z4);
        add8v(b, (done + 1 < db) ? vb1 : z4);
        add8v(b, (done + 2 < db) ? vb2 : z4);
    }
    u32x4 oa, ob;
    oa[0] = packbf2(a[0], a[1]); oa[1] = packbf2(a[2], a[3]);
    oa[2] = packbf2(a[4], a[5]); oa[3] = packbf2(a[6], a[7]);
    ob[0] = packbf2(b[0], b[1]); ob[1] = packbf2(b[2], b[3]);
    ob[2] = packbf2(b[4], b[5]); ob[3] = packbf2(b[6], b[7]);
    up[(size_t)node * 16 + p] = oa;
    ui[(size_t)node * 16 + p] = ob;
}

// ---- fused dual-relation MLP, 2 row-tiles (128 rows) per block ----
// r16 structure; weight staging via async global_load_lds (16B DMA).
__launch_bounds__(256, 2)
__global__ void k_gemm2(const uint16_t* __restrict__ Up, const uint16_t* __restrict__ Ui,
                        const uint16_t* __restrict__ WF1p, const float* __restrict__ B1p,
                        const uint16_t* __restrict__ WF2p, const float* __restrict__ B2p,
                        const uint16_t* __restrict__ WF1i, const float* __restrict__ B1i,
                        const uint16_t* __restrict__ WF2i, const float* __restrict__ B2i,
                        float* __restrict__ HN, uint16_t* __restrict__ HOUT, int last) {
    __shared__ __align__(16) uint16_t wbuf[16384];        // 32768 B, fragment-order
    __shared__ __align__(16) uint16_t sZ[2][64 * WP];     // 2 x 17408 B, wave-private
    int tid = threadIdx.x;
    int wave = tid >> 6, lane = tid & 63;
    int q = lane >> 4, l16 = lane & 15;
    int rb0 = blockIdx.x * 128 + wave * 16;   // tile 0 rows (this wave's 16)
    int rb1 = rb0 + 64;                       // tile 1 rows

    auto loadA = [&](const uint16_t* U, int rowbase, short8* v) {
        const uint16_t* P = U + (size_t)(rowbase + l16) * DIM + q * 8;
#pragma unroll
        for (int s = 0; s < 4; ++s) v[s] = *(const short8*)(P + s * 32);
    };
    // async weight staging: 8 x 16B per thread, direct global->LDS DMA.
    auto loadw = [&](const uint16_t* WF) {
#pragma unroll
        for (int k = 0; k < 8; ++k)
            async_copy16(WF + (size_t)(tid + k * 256) * 8,
                         &wbuf[(size_t)wave * 512 + (size_t)k * 2048]);
    };
    auto stage1 = [&](const short8* af, const float* B1, int zslot) {
        f32x4 acc1[8];
#pragma unroll
        for (int t = 0; t < 8; ++t) acc1[t] = (f32x4){0.f, 0.f, 0.f, 0.f};
#pragma unroll
        for (int t = 0; t < 8; ++t)
#pragma unroll
            for (int s = 0; s < 4; ++s) {
                short8 bb = *(const short8*)&wbuf[((t * 4 + s) * 64 + lane) * 8];
                acc1[t] = __builtin_amdgcn_mfma_f32_16x16x32_bf16(af[s], bb, acc1[t], 0, 0, 0);
            }
#pragma unroll
        for (int t = 0; t < 8; ++t) {
            float b1v = B1[t * 16 + l16];
#pragma unroll
            for (int r = 0; r < 4; ++r)
                sZ[zslot][(wave * 16 + q * 4 + r) * WP + t * 16 + l16] =
                    ftobf16(fmaxf(acc1[t][r] + b1v, 0.f));
        }
    };
    auto stage2 = [&](int zslot, f32x4* acc2) {
        short8 zf[4];
#pragma unroll
        for (int s = 0; s < 4; ++s)
            zf[s] = *(const short8*)&sZ[zslot][(wave * 16 + l16) * WP + s * 32 + q * 8];
#pragma unroll
        for (int t = 0; t < 8; ++t)
#pragma unroll
            for (int s = 0; s < 4; ++s) {
                short8 bb = *(const short8*)&wbuf[((t * 4 + s) * 64 + lane) * 8];
                acc2[t] = __builtin_amdgcn_mfma_f32_16x16x32_bf16(zf[s], bb, acc2[t], 0, 0, 0);
            }
    };

    f32x4 acc2a[8], acc2b[8];
#pragma unroll
    for (int t = 0; t < 8; ++t) { acc2a[t] = (f32x4){0.f,0.f,0.f,0.f}; acc2b[t] = (f32x4){0.f,0.f,0.f,0.f}; }

    short8 af0[4], af1[4];
    loadw(WF1p);                                       // async, in flight
    loadA(Up, rb0, af0); loadA(Up, rb1, af1);          // relation-p A frags in flight
    __syncthreads();                                   // drains vmcnt: wbuf = W1p
    stage1(af0, B1p, 0); stage1(af1, B1p, 1);
    __syncthreads();                                   // W1p reads done
    loadw(WF2p); __syncthreads();                      // wbuf = W2p
    stage2(0, acc2a); stage2(1, acc2b);
    __syncthreads();                                   // W2p reads done
    loadw(WF1i);                                       // async
    loadA(Ui, rb0, af0); loadA(Ui, rb1, af1);          // relation-i A frags
    __syncthreads();                                   // wbuf = W1i
    stage1(af0, B1i, 0); stage1(af1, B1i, 1);
    __syncthreads();
    loadw(WF2i); __syncthreads();                      // wbuf = W2i
    stage2(0, acc2a); stage2(1, acc2b);

    // epilogue, both tiles
#pragma unroll
    for (int t = 0; t < 8; ++t) {
        int col = t * 16 + l16;
        float b2v = B2p[col] + B2i[col];
#pragma unroll
        for (int r = 0; r < 4; ++r) {
            int row0 = rb0 + q * 4 + r, row1 = rb1 + q * 4 + r;
            float y0 = acc2a[t][r] + b2v, y1 = acc2b[t][r] + b2v;
            if (last) {
                HN[(size_t)row0 * DIM + col] = y0;
                HN[(size_t)row1 * DIM + col] = y1;
            } else {
                HOUT[(size_t)row0 * DIM + col] = ftobf16(fmaxf(y0, 0.f));
                HOUT[(size_t)row1 * DIM + col] = ftobf16(fmaxf(y1, 0.f));
            }
        }
    }
}

// ---- pooling, two-stage, high-parallelism (1024 + 64 blocks) ----
__global__ void k_pool1(const float* __restrict__ HN, const int* __restrict__ starts,
                        float* __restrict__ psum, float* __restrict__ pmax, float* __restrict__ pmin) {
    int g = blockIdx.x, sp = blockIdx.y, t = threadIdx.x;  // 256 threads = 2 row-slots x 128 dims
    int d = t & 127, rh = t >> 7;
    int slot = sp * 2 + rh;                                 // 0..31
    int s0 = starts[g], s1 = starts[g + 1];
    float s = 0.f, mx = -INFINITY, mn = INFINITY;
    for (int i = s0 + slot; i < s1; i += 32) {
        float v = HN[(size_t)i * DIM + d];
        s += v; mx = fmaxf(mx, v); mn = fminf(mn, v);
    }
    int o = (g * 32 + slot) * DIM + d;
    psum[o] = s; pmax[o] = mx; pmin[o] = mn;
}

__global__ void k_pool2(const float* __restrict__ psum, const float* __restrict__ pmax,
                        const float* __restrict__ pmin, const int* __restrict__ starts,
                        float* __restrict__ out) {
    __shared__ float S[4][128];
    int g = blockIdx.x, t = threadIdx.x;  // 128 threads
    float s = 0.f, mx = -INFINITY, mn = INFINITY;
    for (int p = 0; p < 32; ++p) {
        int o = (g * 32 + p) * DIM + t;
        s += psum[o]; mx = fmaxf(mx, pmax[o]); mn = fminf(mn, pmin[o]);
    }
    float cnt = (float)(starts[g + 1] - starts[g]);
    float mean = s / fmaxf(cnt, 1.f);
    S[0][t] = s; S[1][t] = mean; S[2][t] = mx; S[3][t] = mn;
    __syncthreads();
    // out[g,k,d] = concat[g, 4d+k]; concat = [sum|mean|max|min]
#pragma unroll
    for (int k = 0; k < 4; ++k) {
        int j = 4 * t + k;
        out[g * 512 + k * 128 + t] = S[j >> 7][j & 127];
    }
    if (t < 4) out[NGRAPH * 512 + g * 4 + t] = 1.0f;  // batch_mask = True -> 1.0f
}

extern "C" void kernel_launch(void* const* d_in, const int* in_sizes, int n_in,
                              void* d_out, int out_size, void* d_ws, size_t ws_size,
                              hipStream_t stream) {
    const int* x     = (const int*)d_in[0];
    const int* ep    = (const int*)d_in[1];
    const int* ei    = (const int*)d_in[2];
    const int* batch = (const int*)d_in[3];
    const float* te  = (const float*)d_in[4];
    const float* oe  = (const float*)d_in[5];
    const float* w1  = (const float*)d_in[6];
    const float* b1  = (const float*)d_in[7];
    const float* w2  = (const float*)d_in[8];
    const float* b2  = (const float*)d_in[9];
    float* out = (float*)d_out;

    char* w = (char*)d_ws;
    auto alloc = [&](size_t n) { char* p = w; w += (n + 255) & ~(size_t)255; return p; };
    uint16_t* h_bf  = (uint16_t*)alloc((size_t)M_PAD * DIM * 2);
    uint16_t* u_pos = (uint16_t*)alloc((size_t)M_PAD * DIM * 2);
    uint16_t* u_inv = (uint16_t*)alloc((size_t)M_PAD * DIM * 2);
    float*    hn    = (float*)alloc((size_t)M_PAD * DIM * 4);
    uint16_t* wfrag = (uint16_t*)alloc((size_t)12 * 16384 * 2);
    int* rsp  = (int*)alloc((M_NODES + 2) * 4);
    int* rsi  = (int*)alloc((M_NODES + 2) * 4);
    int* degp = (int*)alloc(M_NODES * 4);
    int* degi = (int*)alloc(M_NODES * 4);
    int* csrp = (int*)alloc((size_t)NE * 4);
    int* csri = (int*)alloc((size_t)NE * 4);
    int* bsum = (int*)alloc(2 * SCAN_NB * 4);
    int* boff = (int*)alloc(2 * SCAN_NB * 4);
    int* starts = (int*)alloc((NGRAPH + 1) * 4);
    float* psum = (float*)alloc(NGRAPH * 32 * DIM * 4);
    float* pmax = (float*)alloc(NGRAPH * 32 * DIM * 4);
    float* pmin = (float*)alloc(NGRAPH * 32 * DIM * 4);
    if ((size_t)(w - (char*)d_ws) > ws_size) return;  // fail loudly rather than corrupt

    // Per-edge slot arrays alias u_pos/u_inv (25.6 MB each, dead until
    // k_aggregate2 rewrites them AFTER k_fill is done) -> zero extra workspace.
    int* slotp = (int*)u_pos;
    int* sloti = (int*)u_inv;

    k_setup<<<GB_BOUND, 256, 0, stream>>>(x, (const float2*)te, (const float2*)oe,
                                          (uint32_t*)h_bf, w1, w2, wfrag,
                                          batch, starts, degp, degi);
    k_hist<<<(NE + 255) / 256, 256, 0, stream>>>(ep, ei, degp, degi, slotp, sloti);
    dim3 gs(SCAN_NB, 2);
    k_scan1<<<gs, SCAN_B, 0, stream>>>(degp, degi, rsp, rsi, bsum);
    k_scan2<<<2, 256, 0, stream>>>(bsum, boff);
    k_scan3<<<gs, SCAN_B, 0, stream>>>(rsp, rsi, boff);
    k_fill<<<(NE + 255) / 256, 256, 0, stream>>>(ep, ei, rsp, rsi, slotp, sloti, csrp, csri);

    for (int l = 0; l < 3; ++l) {
        k_aggregate2<<<(M_NODES * 16 + 255) / 256, 256, 0, stream>>>(
            (const u32x4*)h_bf, rsp, csrp, rsi, csri, (u32x4*)u_pos, (u32x4*)u_inv);
        const uint16_t* wfL = wfrag + (size_t)l * 4 * 16384;
        // wfrag per layer: [W1p, W1i, W2p, W2i]
        k_gemm2<<<M_PAD / 128, 256, 0, stream>>>(
            u_pos, u_inv,
            wfL,              b1 + (2 * l) * 128,
            wfL + 2 * 16384,  b2 + (2 * l) * 128,
            wfL + 16384,      b1 + (2 * l + 1) * 128,
            wfL + 3 * 16384,  b2 + (2 * l + 1) * 128,
            hn, h_bf, (l == 2) ? 1 : 0);
    }
    dim3 gp(NGRAPH, 16);
    k_pool1<<<gp, 256, 0, stream>>>(hn, starts, psum, pmax, pmin);
    k_pool2<<<NGRAPH, 128, 0, stream>>>(psum, pmax, pmin, starts, out);
}